// Round 1
// baseline (373.513 us; speedup 1.0000x reference)
//
#include <hip/hip_runtime.h>
#include <hip/hip_bf16.h>
#include <stdint.h>

// ID-GNN collapsed form (see analysis):
//   p_i[n]  = mlp(l=0,i)(x[n])              (W1eff = w1[:128]+w1[128:])
//   s0[j]   = sum_{n in adj(j)} p0[n]
//   dpt     = p1[t]-p0[t]
//   H1tt    = x[t]+s0[t]+selfloop(t)*dpt
//   out[t]  = H1tt + sum_{n in N(t), n!=t} mlp(l=1,0)(x[n]+s0[n]+dpt)
//                  + selfloop(t)*mlp(l=1,1)(H1tt)
// N=256, D=128, L=2. Everything f32, matching reference numerics closely.

#define NN 256   // nodes
#define DD 128   // feature dim

// ---- K1: build symmetric adjacency bitmask (256 rows x 8 u32) -------------
__global__ void k1_build_adj(const int* __restrict__ ei, int E,
                             unsigned* __restrict__ Abits) {
    int tid = threadIdx.x;
    for (int i = tid; i < NN * 8; i += 256) Abits[i] = 0u;
    __syncthreads();
    for (int e = tid; e < E; e += 256) {
        int r = ei[e];
        int c = ei[E + e];
        atomicOr(&Abits[r * 8 + (c >> 5)], 1u << (c & 31));
        atomicOr(&Abits[c * 8 + (r >> 5)], 1u << (r & 31));
    }
}

// ---- K2: layer-0 MLPs for all nodes: p0[n], p1[n] -------------------------
// grid 512 = (node, nn); block 128. thread h computes hidden[h] then out[h].
__global__ void k2_mlp_l0(const float* __restrict__ x,
                          const float* __restrict__ w1,
                          const float* __restrict__ b1,
                          const float* __restrict__ w2,
                          const float* __restrict__ b2,
                          float* __restrict__ p0,
                          float* __restrict__ p1) {
    int n = blockIdx.x >> 1;
    int i = blockIdx.x & 1;      // which pre_nn
    int h = threadIdx.x;
    __shared__ float xs[DD];
    __shared__ float hid[DD];
    xs[h] = x[n * DD + h];
    __syncthreads();
    const float* w1b = w1 + (size_t)i * 2 * DD * DD;  // l=0: (0*2+i)*256*128
    float ha = b1[i * DD + h];
#pragma unroll 4
    for (int k = 0; k < DD; ++k)
        ha += xs[k] * (w1b[k * DD + h] + w1b[(k + DD) * DD + h]);
    hid[h] = fmaxf(ha, 0.f);
    __syncthreads();
    const float* w2b = w2 + (size_t)i * DD * DD;
    float oa = b2[i * DD + h];
#pragma unroll 4
    for (int k = 0; k < DD; ++k)
        oa += hid[k] * w2b[k * DD + h];
    (i ? p1 : p0)[n * DD + h] = oa;
}

// ---- K3: s0[j] = sum over neighbors n of p0[n] ----------------------------
__global__ void k3_s0(const unsigned* __restrict__ Abits,
                      const float* __restrict__ p0,
                      float* __restrict__ s0) {
    int j = blockIdx.x;
    int d = threadIdx.x;
    float acc = 0.f;
    for (int w = 0; w < 8; ++w) {
        unsigned bits = Abits[j * 8 + w];
        while (bits) {
            int b = __ffs(bits) - 1;
            bits &= bits - 1;
            int n = w * 32 + b;
            acc += p0[n * DD + d];
        }
    }
    s0[j * DD + d] = acc;
}

// ---- K4: per-target layer-1 neighbor sum ----------------------------------
// grid 256 targets, block 128. Weights (l=1,nn=0) streamed from L2.
__global__ void k4_main(const float* __restrict__ x,
                        const float* __restrict__ w1,
                        const float* __restrict__ b1,
                        const float* __restrict__ w2,
                        const float* __restrict__ b2,
                        const unsigned* __restrict__ Abits,
                        const float* __restrict__ p0,
                        const float* __restrict__ p1,
                        const float* __restrict__ s0,
                        float* __restrict__ out) {
    int t = blockIdx.x;
    int h = threadIdx.x;
    __shared__ float u[DD];
    __shared__ float hid[DD];
    __shared__ float dpt_s[DD];
    const float* w1b = w1 + (size_t)2 * 2 * DD * DD;  // (1*2+0)*256*128
    const float* w2b = w2 + (size_t)2 * DD * DD;
    float b1v = b1[2 * DD + h];
    float b2v = b2[2 * DD + h];
    float dpt = p1[t * DD + h] - p0[t * DD + h];
    dpt_s[h] = dpt;
    bool sl = (Abits[t * 8 + (t >> 5)] >> (t & 31)) & 1u;
    // running accumulator initialized with H1[t,t]
    float acc = x[t * DD + h] + s0[t * DD + h] + (sl ? dpt : 0.f);
    __syncthreads();
    for (int w = 0; w < 8; ++w) {
        unsigned bits = Abits[t * 8 + w];
        while (bits) {
            int b = __ffs(bits) - 1;
            bits &= bits - 1;
            int n = w * 32 + b;
            if (n == t) continue;  // self handled by K5 (h1 replaces h0)
            u[h] = x[n * DD + h] + s0[n * DD + h] + dpt_s[h];
            __syncthreads();
            float ha = b1v;
#pragma unroll 4
            for (int k = 0; k < DD; ++k)
                ha += u[k] * (w1b[k * DD + h] + w1b[(k + DD) * DD + h]);
            hid[h] = fmaxf(ha, 0.f);
            __syncthreads();
            float oa = b2v;
#pragma unroll 4
            for (int k = 0; k < DD; ++k)
                oa += hid[k] * w2b[k * DD + h];
            acc += oa;
            __syncthreads();  // protect u/hid before next iteration writes
        }
    }
    out[t * DD + h] = acc;
}

// ---- K5: self-loop diagonal term: out[t] += mlp(l=1,nn=1)(H1tt) -----------
__global__ void k5_selfdiag(const float* __restrict__ x,
                            const float* __restrict__ w1,
                            const float* __restrict__ b1,
                            const float* __restrict__ w2,
                            const float* __restrict__ b2,
                            const unsigned* __restrict__ Abits,
                            const float* __restrict__ p0,
                            const float* __restrict__ p1,
                            const float* __restrict__ s0,
                            float* __restrict__ out) {
    int t = blockIdx.x;
    int h = threadIdx.x;
    bool sl = (Abits[t * 8 + (t >> 5)] >> (t & 31)) & 1u;
    if (!sl) return;  // wave-uniform per block
    __shared__ float u[DD];
    __shared__ float hid[DD];
    u[h] = x[t * DD + h] + s0[t * DD + h] + (p1[t * DD + h] - p0[t * DD + h]);
    __syncthreads();
    const float* w1b = w1 + (size_t)3 * 2 * DD * DD;  // (1*2+1)
    const float* w2b = w2 + (size_t)3 * DD * DD;
    float ha = b1[3 * DD + h];
#pragma unroll 4
    for (int k = 0; k < DD; ++k)
        ha += u[k] * (w1b[k * DD + h] + w1b[(k + DD) * DD + h]);
    hid[h] = fmaxf(ha, 0.f);
    __syncthreads();
    float oa = b2[3 * DD + h];
#pragma unroll 4
    for (int k = 0; k < DD; ++k)
        oa += hid[k] * w2b[k * DD + h];
    out[t * DD + h] += oa;
}

extern "C" void kernel_launch(void* const* d_in, const int* in_sizes, int n_in,
                              void* d_out, int out_size, void* d_ws, size_t ws_size,
                              hipStream_t stream) {
    const float* x  = (const float*)d_in[0];
    const float* w1 = (const float*)d_in[1];
    const float* b1 = (const float*)d_in[2];
    const float* w2 = (const float*)d_in[3];
    const float* b2 = (const float*)d_in[4];
    const int* ei   = (const int*)d_in[5];
    const int E = in_sizes[5] / 2;

    float* out = (float*)d_out;

    // workspace layout
    unsigned* Abits = (unsigned*)d_ws;                       // 2048 u32 = 8 KB
    float* p0 = (float*)((char*)d_ws + 8192);                // 128 KB
    float* p1 = p0 + NN * DD;                                // 128 KB
    float* s0 = p1 + NN * DD;                                // 128 KB

    k1_build_adj<<<1, 256, 0, stream>>>(ei, E, Abits);
    k2_mlp_l0<<<2 * NN, DD, 0, stream>>>(x, w1, b1, w2, b2, p0, p1);
    k3_s0<<<NN, DD, 0, stream>>>(Abits, p0, s0);
    k4_main<<<NN, DD, 0, stream>>>(x, w1, b1, w2, b2, Abits, p0, p1, s0, out);
    k5_selfdiag<<<NN, DD, 0, stream>>>(x, w1, b1, w2, b2, Abits, p0, p1, s0, out);
}

// Round 2
// 144.988 us; speedup vs baseline: 2.5762x; 2.5762x over previous
//
#include <hip/hip_runtime.h>
#include <hip/hip_bf16.h>
#include <stdint.h>

// ID-GNN collapsed form:
//   p_i[n]  = mlp(l=0,i)(x[n])          with W1eff = w1[:D]+w1[D:]
//   s0[j]   = sum_{n in adj(j)} p0[n]
//   dp[t]   = p1[t]-p0[t]
//   out[t]  = H1tt + sum_{n in N(t), n!=t} mlp(l1,nn0)(x[n]+s0[n]+dp[t])
//                  + selfloop(t)*mlp(l1,nn1)(H1tt)
//   where H1tt = x[t]+s0[t]+selfloop(t)*dp[t]
// Round-2 restructure: edge-flattened row-parallel MLPs (8 rows/block, ILP-8)
// instead of per-target serial neighbor walk (R1: 270us at 3% VALUBusy).

#define NN 256
#define DD 128
#define ROWS 8

// ---- K_w1eff: W1eff[li][k][h] = w1[li][k][h] + w1[li][k+128][h] -----------
__global__ void k_w1eff(const float* __restrict__ w1, float* __restrict__ w1eff) {
    int idx = blockIdx.x * 256 + threadIdx.x;     // 0..65535
    int li  = idx >> 14;                          // 0..3 (l*2+i)
    int rem = idx & 16383;                        // k*128+h
    w1eff[idx] = w1[li * 32768 + rem] + w1[li * 32768 + rem + 16384];
}

// ---- K1: adjacency bitmask (LDS-built) + flattened edge lists -------------
__global__ void k1_adj_elist(const int* __restrict__ ei, int E,
                             unsigned* __restrict__ Abits,
                             unsigned* __restrict__ ecnt,
                             int* __restrict__ elist0,
                             int* __restrict__ elist1) {
    __shared__ unsigned sb[NN * 8];
    int tid = threadIdx.x;
    for (int i = tid; i < NN * 8; i += 256) sb[i] = 0u;
    if (tid < 2) ecnt[tid] = 0u;
    __syncthreads();
    for (int e = tid; e < E; e += 256) {
        int r = ei[e], c = ei[E + e];
        atomicOr(&sb[r * 8 + (c >> 5)], 1u << (c & 31));
        atomicOr(&sb[c * 8 + (r >> 5)], 1u << (r & 31));
    }
    __syncthreads();
    // publish bitmask for later kernels
    for (int i = tid; i < NN * 8; i += 256) Abits[i] = sb[i];
    // per-target extraction: thread t handles target t
    int t = tid;
    unsigned bw[8];
    int cnt = 0;
    for (int w = 0; w < 8; ++w) { bw[w] = sb[t * 8 + w]; cnt += __popc(bw[w]); }
    bool sl = (bw[t >> 5] >> (t & 31)) & 1u;
    if (sl) cnt -= 1;
    unsigned pos = atomicAdd(&ecnt[0], (unsigned)cnt);
    for (int w = 0; w < 8; ++w) {
        unsigned bits = bw[w];
        while (bits) {
            int b = __ffs(bits) - 1; bits &= bits - 1;
            int n = w * 32 + b;
            if (n != t) elist0[pos++] = (t << 8) | n;
        }
    }
    if (sl) { unsigned q = atomicAdd(&ecnt[1], 1u); elist1[q] = (t << 8) | t; }
}

// ---- K2: layer-0 MLPs, row-parallel (8 nodes/block) -----------------------
// grid 64: blocks 0..31 -> nn0 (p0), 32..63 -> nn1 (p1)
__global__ void k2_mlp_l0(const float* __restrict__ x,
                          const float* __restrict__ w1eff,
                          const float* __restrict__ b1,
                          const float* __restrict__ w2,
                          const float* __restrict__ b2,
                          float* __restrict__ p0, float* __restrict__ p1) {
    int i  = blockIdx.x >> 5;
    int nb = blockIdx.x & 31;
    int h  = threadIdx.x;
    const float* w1e = w1eff + i * 16384;
    const float* w2b = w2 + i * 16384;           // l=0 base
    float b1v = b1[i * DD + h], b2v = b2[i * DD + h];
    __shared__ float u[ROWS * DD];               // layout u[k*8 + r]
    float v[ROWS];
#pragma unroll
    for (int r = 0; r < ROWS; ++r) v[r] = x[(nb * ROWS + r) * DD + h];
    ((float4*)u)[h * 2]     = make_float4(v[0], v[1], v[2], v[3]);
    ((float4*)u)[h * 2 + 1] = make_float4(v[4], v[5], v[6], v[7]);
    __syncthreads();
    float acc[ROWS];
#pragma unroll
    for (int r = 0; r < ROWS; ++r) acc[r] = b1v;
#pragma unroll 4
    for (int k = 0; k < DD; ++k) {
        float wv = w1e[k * DD + h];
        float4 ua = ((float4*)u)[k * 2], ub = ((float4*)u)[k * 2 + 1];
        acc[0] += ua.x * wv; acc[1] += ua.y * wv; acc[2] += ua.z * wv; acc[3] += ua.w * wv;
        acc[4] += ub.x * wv; acc[5] += ub.y * wv; acc[6] += ub.z * wv; acc[7] += ub.w * wv;
    }
    __syncthreads();
    ((float4*)u)[h * 2]     = make_float4(fmaxf(acc[0],0.f), fmaxf(acc[1],0.f),
                                          fmaxf(acc[2],0.f), fmaxf(acc[3],0.f));
    ((float4*)u)[h * 2 + 1] = make_float4(fmaxf(acc[4],0.f), fmaxf(acc[5],0.f),
                                          fmaxf(acc[6],0.f), fmaxf(acc[7],0.f));
    __syncthreads();
#pragma unroll
    for (int r = 0; r < ROWS; ++r) acc[r] = b2v;
#pragma unroll 4
    for (int k = 0; k < DD; ++k) {
        float wv = w2b[k * DD + h];
        float4 ua = ((float4*)u)[k * 2], ub = ((float4*)u)[k * 2 + 1];
        acc[0] += ua.x * wv; acc[1] += ua.y * wv; acc[2] += ua.z * wv; acc[3] += ua.w * wv;
        acc[4] += ub.x * wv; acc[5] += ub.y * wv; acc[6] += ub.z * wv; acc[7] += ub.w * wv;
    }
    float* pout = i ? p1 : p0;
#pragma unroll
    for (int r = 0; r < ROWS; ++r) pout[(nb * ROWS + r) * DD + h] = acc[r];
}

// ---- K3: s0[j], dp[j], and out init = H1[j,j] -----------------------------
__global__ void k3_s0_dp_init(const unsigned* __restrict__ Abits,
                              const float* __restrict__ x,
                              const float* __restrict__ p0,
                              const float* __restrict__ p1,
                              float* __restrict__ s0, float* __restrict__ dp,
                              float* __restrict__ out) {
    int j = blockIdx.x, d = threadIdx.x;
    float acc = 0.f;
    for (int w = 0; w < 8; ++w) {
        unsigned bits = Abits[j * 8 + w];
        while (bits) {
            int b = __ffs(bits) - 1; bits &= bits - 1;
            acc += p0[(w * 32 + b) * DD + d];
        }
    }
    float dv = p1[j * DD + d] - p0[j * DD + d];
    s0[j * DD + d] = acc;
    dp[j * DD + d] = dv;
    bool sl = (Abits[j * 8 + (j >> 5)] >> (j & 31)) & 1u;
    out[j * DD + d] = x[j * DD + d] + acc + (sl ? dv : 0.f);
}

// ---- K4: generic row-parallel layer-1 MLP over an edge list ---------------
// u_row = x[n]+s0[n]+dp[t]; result atomicAdd'ed into out[t].
__global__ void k4_rows(const int* __restrict__ elist,
                        const unsigned* __restrict__ cntp,
                        const float* __restrict__ w1e,
                        const float* __restrict__ b1b,
                        const float* __restrict__ w2b,
                        const float* __restrict__ b2b,
                        const float* __restrict__ x,
                        const float* __restrict__ s0,
                        const float* __restrict__ dp,
                        float* __restrict__ out) {
    int cnt = (int)*cntp;
    int r0  = blockIdx.x * ROWS;
    if (r0 >= cnt) return;
    int h  = threadIdx.x;
    int nr = min(ROWS, cnt - r0);
    __shared__ float u[ROWS * DD];               // u[k*8 + r]
    int   tarr[ROWS];
    float v[ROWS];
#pragma unroll
    for (int r = 0; r < ROWS; ++r) {
        if (r < nr) {
            int pr = elist[r0 + r];
            int t = pr >> 8, n = pr & 255;
            tarr[r] = t;
            v[r] = x[n * DD + h] + s0[n * DD + h] + dp[t * DD + h];
        } else { tarr[r] = -1; v[r] = 0.f; }
    }
    ((float4*)u)[h * 2]     = make_float4(v[0], v[1], v[2], v[3]);
    ((float4*)u)[h * 2 + 1] = make_float4(v[4], v[5], v[6], v[7]);
    float b1v = b1b[h], b2v = b2b[h];
    __syncthreads();
    float acc[ROWS];
#pragma unroll
    for (int r = 0; r < ROWS; ++r) acc[r] = b1v;
#pragma unroll 4
    for (int k = 0; k < DD; ++k) {
        float wv = w1e[k * DD + h];
        float4 ua = ((float4*)u)[k * 2], ub = ((float4*)u)[k * 2 + 1];
        acc[0] += ua.x * wv; acc[1] += ua.y * wv; acc[2] += ua.z * wv; acc[3] += ua.w * wv;
        acc[4] += ub.x * wv; acc[5] += ub.y * wv; acc[6] += ub.z * wv; acc[7] += ub.w * wv;
    }
    __syncthreads();
    ((float4*)u)[h * 2]     = make_float4(fmaxf(acc[0],0.f), fmaxf(acc[1],0.f),
                                          fmaxf(acc[2],0.f), fmaxf(acc[3],0.f));
    ((float4*)u)[h * 2 + 1] = make_float4(fmaxf(acc[4],0.f), fmaxf(acc[5],0.f),
                                          fmaxf(acc[6],0.f), fmaxf(acc[7],0.f));
    __syncthreads();
#pragma unroll
    for (int r = 0; r < ROWS; ++r) acc[r] = b2v;
#pragma unroll 4
    for (int k = 0; k < DD; ++k) {
        float wv = w2b[k * DD + h];
        float4 ua = ((float4*)u)[k * 2], ub = ((float4*)u)[k * 2 + 1];
        acc[0] += ua.x * wv; acc[1] += ua.y * wv; acc[2] += ua.z * wv; acc[3] += ua.w * wv;
        acc[4] += ub.x * wv; acc[5] += ub.y * wv; acc[6] += ub.z * wv; acc[7] += ub.w * wv;
    }
#pragma unroll
    for (int r = 0; r < ROWS; ++r)
        if (r < nr) atomicAdd(&out[tarr[r] * DD + h], acc[r]);
}

extern "C" void kernel_launch(void* const* d_in, const int* in_sizes, int n_in,
                              void* d_out, int out_size, void* d_ws, size_t ws_size,
                              hipStream_t stream) {
    const float* x  = (const float*)d_in[0];
    const float* w1 = (const float*)d_in[1];
    const float* b1 = (const float*)d_in[2];
    const float* w2 = (const float*)d_in[3];
    const float* b2 = (const float*)d_in[4];
    const int* ei   = (const int*)d_in[5];
    const int E = in_sizes[5] / 2;
    float* out = (float*)d_out;

    // workspace layout
    unsigned* Abits = (unsigned*)d_ws;            // 2048 u32
    unsigned* ecnt  = Abits + 2048;               // 2 u32
    int* elist0     = (int*)(Abits + 2052);       // 4096 int
    int* elist1     = elist0 + 4096;              // 256 int
    float* w1eff    = (float*)(elist1 + 256);     // 4*16384 f32
    float* p0       = w1eff + 4 * 16384;          // 256*128 f32
    float* p1       = p0 + NN * DD;
    float* s0       = p1 + NN * DD;
    float* dp       = s0 + NN * DD;

    k_w1eff<<<256, 256, 0, stream>>>(w1, w1eff);
    k1_adj_elist<<<1, 256, 0, stream>>>(ei, E, Abits, ecnt, elist0, elist1);
    k2_mlp_l0<<<64, DD, 0, stream>>>(x, w1eff, b1, w2, b2, p0, p1);
    k3_s0_dp_init<<<NN, DD, 0, stream>>>(Abits, x, p0, p1, s0, dp, out);
    // layer-1 nn0 over neighbor edges (max 2E = 4096 rows -> 512 blocks)
    k4_rows<<<512, DD, 0, stream>>>(elist0, &ecnt[0],
                                    w1eff + 2 * 16384, b1 + 2 * DD,
                                    w2 + 2 * 16384, b2 + 2 * DD,
                                    x, s0, dp, out);
    // layer-1 nn1 over self-loop targets (max 256 rows -> 32 blocks)
    k4_rows<<<32, DD, 0, stream>>>(elist1, &ecnt[1],
                                   w1eff + 3 * 16384, b1 + 3 * DD,
                                   w2 + 3 * 16384, b2 + 3 * DD,
                                   x, s0, dp, out);
}